// Round 5
// baseline (180.380 us; speedup 1.0000x reference)
//
#include <hip/hip_runtime.h>
#include <hip/hip_bf16.h>

#define B_ 4
#define N_ 4096
#define C_ 64
#define NW_ (N_ / 32)            // mask words per row = 128

constexpr float LOG2E = 1.44269504088896340736f;

typedef __attribute__((ext_vector_type(8))) short short8;
typedef __attribute__((ext_vector_type(4))) float f32x4;

#if __has_builtin(__builtin_amdgcn_exp2f)
#define EXP2F(x) __builtin_amdgcn_exp2f(x)
#else
#define EXP2F(x) exp2f(x)
#endif

static __device__ inline short f32_to_bf16_bits(float f) {
    union { __hip_bfloat16 h; unsigned short u; } cv;
    cv.h = __float2bfloat16(f);
    return (short)cv.u;
}

// ---------------------------------------------------------------------------
// Fused prep: per (b, 64-row tile):
//   s1[b,i] = (h[b,i,:]@a1)*log2e ; s2 likewise
//   hT[b][c][j] = bf16(h[b][j][c])
// ---------------------------------------------------------------------------
__global__ __launch_bounds__(256) void gat_prep(
    const float* __restrict__ h, const float* __restrict__ a,
    float* __restrict__ s1s, float* __restrict__ s2s,
    unsigned short* __restrict__ hT)
{
    const int bid = blockIdx.x;                 // B * N/64 = 256
    const int b = bid >> 6;
    const int i0 = (bid & 63) * 64;
    __shared__ float tile[64][65];
    const int t = threadIdx.x;
    {
        const int rr = t >> 2;                  // local row (j)
        const int cc = (t & 3) * 16;            // channel chunk
        const float* src = h + ((size_t)(b * N_ + i0 + rr)) * C_ + cc;
        float d1 = 0.f, d2 = 0.f;
#pragma unroll
        for (int k = 0; k < 16; k += 4) {
            float4 v = *(const float4*)(src + k);
            tile[rr][cc + k + 0] = v.x;
            tile[rr][cc + k + 1] = v.y;
            tile[rr][cc + k + 2] = v.z;
            tile[rr][cc + k + 3] = v.w;
            float4 a1 = *(const float4*)(a + cc + k);
            float4 a2 = *(const float4*)(a + C_ + cc + k);
            d1 += v.x * a1.x + v.y * a1.y + v.z * a1.z + v.w * a1.w;
            d2 += v.x * a2.x + v.y * a2.y + v.z * a2.z + v.w * a2.w;
        }
        // 4 consecutive lanes hold partial dots of the same row
        d1 += __shfl_xor(d1, 1, 64); d1 += __shfl_xor(d1, 2, 64);
        d2 += __shfl_xor(d2, 1, 64); d2 += __shfl_xor(d2, 2, 64);
        if ((t & 3) == 0) {
            s1s[b * N_ + i0 + rr] = d1 * LOG2E;
            s2s[b * N_ + i0 + rr] = d2 * LOG2E;
        }
    }
    __syncthreads();
    {
        const int c  = t >> 2;                  // channel
        const int ic = (t & 3) * 16;            // j chunk
        short8 w0, w1;
#pragma unroll
        for (int k = 0; k < 8; ++k)
            w0[k] = f32_to_bf16_bits(tile[ic + k][c]);
#pragma unroll
        for (int k = 0; k < 8; ++k)
            w1[k] = f32_to_bf16_bits(tile[ic + 8 + k][c]);
        unsigned short* dst = hT + ((size_t)(b * C_ + c)) * N_ + i0 + ic;
        *(short8*)(dst)     = w0;
        *(short8*)(dst + 8) = w1;
    }
}

// ---------------------------------------------------------------------------
// Mask precompute: maskT[w][i] = bits of (adj[i][w*32+q] > 0.5), q=bit index.
// One wave per row; 64 j per ballot step; transposed layout for the main
// kernel's coalesced per-row word loads. 64 MB read (HBM), 2 MB written.
// ---------------------------------------------------------------------------
__global__ __launch_bounds__(256) void gat_mask(
    const float* __restrict__ adj, unsigned int* __restrict__ maskT)
{
    const int wave = threadIdx.x >> 6;
    const int lane = threadIdx.x & 63;
    const int row = blockIdx.x * 4 + wave;      // 0..N-1
    const float* arow = adj + (size_t)row * N_;
#pragma unroll 4
    for (int jw = 0; jw < N_ / 64; ++jw) {
        float v = arow[jw * 64 + lane];
        unsigned long long bal = __ballot(v > 0.5f);
        if (lane == 0)
            maskT[(size_t)(2 * jw) * N_ + row] = (unsigned int)bal;
        else if (lane == 32)
            maskT[(size_t)(2 * jw + 1) * N_ + row] = (unsigned int)(bal >> 32);
    }
}

// ---------------------------------------------------------------------------
// Main kernel: masked-softmax numerator + PV with fixed zero max reference.
// ITILE=32 rows/wave. Grid: 128 i-tiles * jsNum = 1024 blocks. 4 waves = 4
// batches. All inputs (maskT 2MB, hT 2MB, s2 64KB) are L2-resident; the only
// HBM traffic is the accP/lP partial writes. l via ones-MFMA (free pipe).
// ---------------------------------------------------------------------------
__global__ __launch_bounds__(256) void gat_main(
    const unsigned int* __restrict__ maskT, const float* __restrict__ s1s,
    const float* __restrict__ s2s, const unsigned short* __restrict__ hT,
    float* __restrict__ accP, float* __restrict__ lP, int jsNum)
{
    const int bid  = blockIdx.x;
    const int itb  = bid / jsNum;               // 0..127
    const int js   = bid % jsNum;
    const int jlen = N_ / jsNum;
    const int j0   = js * jlen;
    const int i0   = itb * 32;
    const int lane = threadIdx.x & 63;
    const int b    = threadIdx.x >> 6;          // one batch per wave
    const int g    = lane >> 4;
    const int r16  = lane & 15;

    float s1v[2];
    s1v[0] = s1s[b * N_ + i0 + r16];
    s1v[1] = s1s[b * N_ + i0 + 16 + r16];

    f32x4 acc[2][4];
#pragma unroll
    for (int it = 0; it < 2; ++it)
#pragma unroll
        for (int ct = 0; ct < 4; ++ct)
            acc[it][ct] = (f32x4){0.f, 0.f, 0.f, 0.f};
    f32x4 accL[2];
    accL[0] = (f32x4){0.f, 0.f, 0.f, 0.f};
    accL[1] = (f32x4){0.f, 0.f, 0.f, 0.f};

    short8 ones;
#pragma unroll
    for (int q = 0; q < 8; ++q) ones[q] = (short)0x3F80;   // bf16(1.0)

    const unsigned short* hTb = hT + (size_t)b * C_ * N_;
    const float* s2b = s2s + b * N_;
    const int kbase = j0 + g * 8;
    const int gsh = g * 8;

    for (int jj = 0; jj < jlen; jj += 32) {
        const int kb = kbase + jj;
        const int w = (j0 + jj) >> 5;           // mask word index

        short8 bfrag[4];
#pragma unroll
        for (int ct = 0; ct < 4; ++ct)
            bfrag[ct] = *(const short8*)(hTb + (size_t)(ct * 16 + r16) * N_ + kb);

        float4 sa = *(const float4*)(s2b + kb);
        float4 sb = *(const float4*)(s2b + kb + 4);
        float s2v[8] = {sa.x, sa.y, sa.z, sa.w, sb.x, sb.y, sb.z, sb.w};

        const unsigned int* mw = maskT + (size_t)w * N_ + i0;
        unsigned int m0 = mw[r16] >> gsh;
        unsigned int m1 = mw[16 + r16] >> gsh;

#pragma unroll
        for (int it = 0; it < 2; ++it) {
            const float s1 = s1v[it];
            const unsigned int m = it ? m1 : m0;
            short8 afrag;
#pragma unroll
            for (int q = 0; q < 8; ++q) {
                float e = s1 + s2v[q];
                e = fmaxf(e, 0.2f * e);          // leaky relu (scale-invariant)
                float p = ((m >> q) & 1u) ? EXP2F(e) : 0.0f;
                afrag[q] = f32_to_bf16_bits(p);
            }
#pragma unroll
            for (int ct = 0; ct < 4; ++ct)
                acc[it][ct] = __builtin_amdgcn_mfma_f32_16x16x32_bf16(
                    afrag, bfrag[ct], acc[it][ct], 0, 0, 0);
            accL[it] = __builtin_amdgcn_mfma_f32_16x16x32_bf16(
                afrag, ones, accL[it], 0, 0, 0);
        }
    }

    const size_t pb = (size_t)js * B_ + b;
    // accL[it][r] at any column holds rowsum(row = g*4+r); col r16==0 writes.
    if (r16 == 0) {
#pragma unroll
        for (int it = 0; it < 2; ++it)
#pragma unroll
            for (int r = 0; r < 4; ++r)
                lP[pb * N_ + i0 + it * 16 + g * 4 + r] = accL[it][r];
    }

    float* accBase = accP + pb * (size_t)N_ * C_;
#pragma unroll
    for (int it = 0; it < 2; ++it)
#pragma unroll
        for (int ct = 0; ct < 4; ++ct)
#pragma unroll
            for (int r = 0; r < 4; ++r) {
                const int i = i0 + it * 16 + g * 4 + r;
                const int c = ct * 16 + r16;
                accBase[(size_t)i * C_ + c] = acc[it][ct][r];
            }
}

// ---------------------------------------------------------------------------
// Combine: out = elu( (sum_p acc_p) / (sum_p l_p) ), float4 per thread
// ---------------------------------------------------------------------------
__global__ __launch_bounds__(256) void gat_combine(
    const float* __restrict__ accP, const float* __restrict__ lP,
    float* __restrict__ out, int jsNum)
{
    const int t = blockIdx.x * 256 + threadIdx.x;      // one float4
    const int total4 = B_ * N_ * C_ / 4;
    if (t >= total4) return;
    const int bi = t >> 4;                             // (t*4)/C_
    float4 asum = {0.f, 0.f, 0.f, 0.f};
    float lsum = 0.f;
    for (int p = 0; p < jsNum; ++p) {
        float4 v = ((const float4*)accP)[(size_t)p * total4 + t];
        asum.x += v.x; asum.y += v.y; asum.z += v.z; asum.w += v.w;
        lsum += lP[(size_t)p * (B_ * N_) + bi];
    }
    const float inv = 1.0f / lsum;
    float4 o;
    o.x = asum.x * inv; o.y = asum.y * inv; o.z = asum.z * inv; o.w = asum.w * inv;
    o.x = (o.x > 0.f) ? o.x : (expf(o.x) - 1.f);
    o.y = (o.y > 0.f) ? o.y : (expf(o.y) - 1.f);
    o.z = (o.z > 0.f) ? o.z : (expf(o.z) - 1.f);
    o.w = (o.w > 0.f) ? o.w : (expf(o.w) - 1.f);
    ((float4*)out)[t] = o;
}

// ---------------------------------------------------------------------------
extern "C" void kernel_launch(void* const* d_in, const int* in_sizes, int n_in,
                              void* d_out, int out_size, void* d_ws, size_t ws_size,
                              hipStream_t stream)
{
    const float* h   = (const float*)d_in[0];   // (B,N,C) f32
    const float* adj = (const float*)d_in[1];   // (N,N)   f32
    const float* a   = (const float*)d_in[2];   // (2C,1)  f32
    float* out = (float*)d_out;

    char* ws = (char*)d_ws;
    float* s1s = (float*)ws;                                    // B*N f32
    float* s2s = (float*)(ws + (size_t)B_ * N_ * 4);            // B*N f32
    unsigned short* hT = (unsigned short*)(ws + (size_t)2 * B_ * N_ * 4);
    const size_t maskOff = (size_t)2 * B_ * N_ * 4 + (size_t)B_ * C_ * N_ * 2;
    unsigned int* maskT = (unsigned int*)(ws + maskOff);        // NW_*N_ u32
    const size_t lOff = maskOff + (size_t)NW_ * N_ * 4;

    int jsNum = 8;
    while (jsNum > 1) {
        size_t need = lOff + (size_t)jsNum * B_ * N_ * 4
                           + (size_t)jsNum * B_ * N_ * C_ * 4;
        if (need <= ws_size) break;
        jsNum >>= 1;
    }
    float* lP   = (float*)(ws + lOff);
    float* accP = (float*)(ws + lOff + (size_t)jsNum * B_ * N_ * 4);

    gat_prep<<<B_ * (N_ / 64), 256, 0, stream>>>(h, a, s1s, s2s, hT);
    gat_mask<<<N_ / 4, 256, 0, stream>>>(adj, maskT);
    gat_main<<<128 * jsNum, 256, 0, stream>>>(maskT, s1s, s2s, hT, accP, lP, jsNum);
    gat_combine<<<(B_ * N_ * C_ / 4 + 255) / 256, 256, 0, stream>>>(accP, lP, out, jsNum);
}

// Round 6
// 155.630 us; speedup vs baseline: 1.1590x; 1.1590x over previous
//
#include <hip/hip_runtime.h>
#include <hip/hip_bf16.h>

#define B_ 4
#define N_ 4096
#define C_ 64
#define NW_ (N_ / 32)            // mask words per row = 128

constexpr float LOG2E = 1.44269504088896340736f;

typedef __attribute__((ext_vector_type(8))) short short8;
typedef __attribute__((ext_vector_type(4))) float f32x4;

#if __has_builtin(__builtin_amdgcn_exp2f)
#define EXP2F(x) __builtin_amdgcn_exp2f(x)
#else
#define EXP2F(x) exp2f(x)
#endif

static __device__ inline short f32_to_bf16_bits(float f) {
    union { __hip_bfloat16 h; unsigned short u; } cv;
    cv.h = __float2bfloat16(f);
    return (short)cv.u;
}

// ---------------------------------------------------------------------------
// Fused prep: per (b, 64-row tile):
//   s1[b,i] = (h[b,i,:]@a1)*log2e ; s2 likewise
//   hT[b][c][j] = bf16(h[b][j][c])
// ---------------------------------------------------------------------------
__global__ __launch_bounds__(256) void gat_prep(
    const float* __restrict__ h, const float* __restrict__ a,
    float* __restrict__ s1s, float* __restrict__ s2s,
    unsigned short* __restrict__ hT)
{
    const int bid = blockIdx.x;                 // B * N/64 = 256
    const int b = bid >> 6;
    const int i0 = (bid & 63) * 64;
    __shared__ float tile[64][65];
    const int t = threadIdx.x;
    {
        const int rr = t >> 2;                  // local row (j)
        const int cc = (t & 3) * 16;            // channel chunk
        const float* src = h + ((size_t)(b * N_ + i0 + rr)) * C_ + cc;
        float d1 = 0.f, d2 = 0.f;
#pragma unroll
        for (int k = 0; k < 16; k += 4) {
            float4 v = *(const float4*)(src + k);
            tile[rr][cc + k + 0] = v.x;
            tile[rr][cc + k + 1] = v.y;
            tile[rr][cc + k + 2] = v.z;
            tile[rr][cc + k + 3] = v.w;
            float4 a1 = *(const float4*)(a + cc + k);
            float4 a2 = *(const float4*)(a + C_ + cc + k);
            d1 += v.x * a1.x + v.y * a1.y + v.z * a1.z + v.w * a1.w;
            d2 += v.x * a2.x + v.y * a2.y + v.z * a2.z + v.w * a2.w;
        }
        // 4 consecutive lanes hold partial dots of the same row
        d1 += __shfl_xor(d1, 1, 64); d1 += __shfl_xor(d1, 2, 64);
        d2 += __shfl_xor(d2, 1, 64); d2 += __shfl_xor(d2, 2, 64);
        if ((t & 3) == 0) {
            s1s[b * N_ + i0 + rr] = d1 * LOG2E;
            s2s[b * N_ + i0 + rr] = d2 * LOG2E;
        }
    }
    __syncthreads();
    {
        const int c  = t >> 2;                  // channel
        const int ic = (t & 3) * 16;            // j chunk
        short8 w0, w1;
#pragma unroll
        for (int k = 0; k < 8; ++k)
            w0[k] = f32_to_bf16_bits(tile[ic + k][c]);
#pragma unroll
        for (int k = 0; k < 8; ++k)
            w1[k] = f32_to_bf16_bits(tile[ic + 8 + k][c]);
        unsigned short* dst = hT + ((size_t)(b * C_ + c)) * N_ + i0 + ic;
        *(short8*)(dst)     = w0;
        *(short8*)(dst + 8) = w1;
    }
}

// ---------------------------------------------------------------------------
// Mask precompute (ballot-free, deep-MLP): each thread reads 64 consecutive
// floats of one adj row (16 independent float4 loads), builds 2 mask words
// with per-lane cmp/or only, stores 2 dwords at the end (no mid-loop stores
// sharing vmcnt with the load stream — the round-5 serialization bug).
// Tile: 32 rows x 512 cols per block; grid 128*8=1024.
// Layout: maskT[w][i], w = global column word, bit q = column w*32+q.
// ---------------------------------------------------------------------------
__global__ __launch_bounds__(256) void gat_mask(
    const float* __restrict__ adj, unsigned int* __restrict__ maskT)
{
    const int bid = blockIdx.x;                 // 128 row-tiles * 8 col-tiles
    const int i0  = (bid >> 3) * 32;
    const int j0  = (bid & 7) * 512;
    const int t   = threadIdx.x;
    const int row = i0 + (t & 31);
    const int jc  = j0 + (t >> 5) * 64;

    const float* src = adj + (size_t)row * N_ + jc;

    float4 v0  = *(const float4*)(src +  0); float4 v1  = *(const float4*)(src +  4);
    float4 v2  = *(const float4*)(src +  8); float4 v3  = *(const float4*)(src + 12);
    float4 v4  = *(const float4*)(src + 16); float4 v5  = *(const float4*)(src + 20);
    float4 v6  = *(const float4*)(src + 24); float4 v7  = *(const float4*)(src + 28);
    float4 v8  = *(const float4*)(src + 32); float4 v9  = *(const float4*)(src + 36);
    float4 v10 = *(const float4*)(src + 40); float4 v11 = *(const float4*)(src + 44);
    float4 v12 = *(const float4*)(src + 48); float4 v13 = *(const float4*)(src + 52);
    float4 v14 = *(const float4*)(src + 56); float4 v15 = *(const float4*)(src + 60);

#define NIB(vv, sh, W) \
    W |= (vv.x > 0.5f ? 1u : 0u) << (sh); \
    W |= (vv.y > 0.5f ? 2u : 0u) << (sh); \
    W |= (vv.z > 0.5f ? 4u : 0u) << (sh); \
    W |= (vv.w > 0.5f ? 8u : 0u) << (sh);

    unsigned int w0 = 0u, w1 = 0u;
    NIB(v0,  0, w0) NIB(v1,  4, w0) NIB(v2,  8, w0) NIB(v3, 12, w0)
    NIB(v4, 16, w0) NIB(v5, 20, w0) NIB(v6, 24, w0) NIB(v7, 28, w0)
    NIB(v8,  0, w1) NIB(v9,  4, w1) NIB(v10, 8, w1) NIB(v11,12, w1)
    NIB(v12,16, w1) NIB(v13,20, w1) NIB(v14,24, w1) NIB(v15,28, w1)
#undef NIB

    const int wb = jc >> 5;
    maskT[(size_t)wb * N_ + row]       = w0;
    maskT[(size_t)(wb + 1) * N_ + row] = w1;
}

// ---------------------------------------------------------------------------
// Main kernel: masked-softmax numerator + PV with fixed zero max reference.
// ITILE=32 rows/wave. Grid: 128 i-tiles * jsNum = 1024 blocks. 4 waves = 4
// batches. All inputs (maskT 2MB, hT 2MB, s2 64KB) are L2-resident; the only
// HBM traffic is the accP/lP partial writes. l via ones-MFMA (free pipe).
// ---------------------------------------------------------------------------
__global__ __launch_bounds__(256) void gat_main(
    const unsigned int* __restrict__ maskT, const float* __restrict__ s1s,
    const float* __restrict__ s2s, const unsigned short* __restrict__ hT,
    float* __restrict__ accP, float* __restrict__ lP, int jsNum)
{
    const int bid  = blockIdx.x;
    const int itb  = bid / jsNum;               // 0..127
    const int js   = bid % jsNum;
    const int jlen = N_ / jsNum;
    const int j0   = js * jlen;
    const int i0   = itb * 32;
    const int lane = threadIdx.x & 63;
    const int b    = threadIdx.x >> 6;          // one batch per wave
    const int g    = lane >> 4;
    const int r16  = lane & 15;

    float s1v[2];
    s1v[0] = s1s[b * N_ + i0 + r16];
    s1v[1] = s1s[b * N_ + i0 + 16 + r16];

    f32x4 acc[2][4];
#pragma unroll
    for (int it = 0; it < 2; ++it)
#pragma unroll
        for (int ct = 0; ct < 4; ++ct)
            acc[it][ct] = (f32x4){0.f, 0.f, 0.f, 0.f};
    f32x4 accL[2];
    accL[0] = (f32x4){0.f, 0.f, 0.f, 0.f};
    accL[1] = (f32x4){0.f, 0.f, 0.f, 0.f};

    short8 ones;
#pragma unroll
    for (int q = 0; q < 8; ++q) ones[q] = (short)0x3F80;   // bf16(1.0)

    const unsigned short* hTb = hT + (size_t)b * C_ * N_;
    const float* s2b = s2s + b * N_;
    const int kbase = j0 + g * 8;
    const int gsh = g * 8;

    for (int jj = 0; jj < jlen; jj += 32) {
        const int kb = kbase + jj;
        const int w = (j0 + jj) >> 5;           // mask word index

        short8 bfrag[4];
#pragma unroll
        for (int ct = 0; ct < 4; ++ct)
            bfrag[ct] = *(const short8*)(hTb + (size_t)(ct * 16 + r16) * N_ + kb);

        float4 sa = *(const float4*)(s2b + kb);
        float4 sb = *(const float4*)(s2b + kb + 4);
        float s2v[8] = {sa.x, sa.y, sa.z, sa.w, sb.x, sb.y, sb.z, sb.w};

        const unsigned int* mw = maskT + (size_t)w * N_ + i0;
        unsigned int m0 = mw[r16] >> gsh;
        unsigned int m1 = mw[16 + r16] >> gsh;

#pragma unroll
        for (int it = 0; it < 2; ++it) {
            const float s1 = s1v[it];
            const unsigned int m = it ? m1 : m0;
            short8 afrag;
#pragma unroll
            for (int q = 0; q < 8; ++q) {
                float e = s1 + s2v[q];
                e = fmaxf(e, 0.2f * e);          // leaky relu (scale-invariant)
                float p = ((m >> q) & 1u) ? EXP2F(e) : 0.0f;
                afrag[q] = f32_to_bf16_bits(p);
            }
#pragma unroll
            for (int ct = 0; ct < 4; ++ct)
                acc[it][ct] = __builtin_amdgcn_mfma_f32_16x16x32_bf16(
                    afrag, bfrag[ct], acc[it][ct], 0, 0, 0);
            accL[it] = __builtin_amdgcn_mfma_f32_16x16x32_bf16(
                afrag, ones, accL[it], 0, 0, 0);
        }
    }

    const size_t pb = (size_t)js * B_ + b;
    // accL[it][r] at any column holds rowsum(row = g*4+r); col r16==0 writes.
    if (r16 == 0) {
#pragma unroll
        for (int it = 0; it < 2; ++it)
#pragma unroll
            for (int r = 0; r < 4; ++r)
                lP[pb * N_ + i0 + it * 16 + g * 4 + r] = accL[it][r];
    }

    float* accBase = accP + pb * (size_t)N_ * C_;
#pragma unroll
    for (int it = 0; it < 2; ++it)
#pragma unroll
        for (int ct = 0; ct < 4; ++ct)
#pragma unroll
            for (int r = 0; r < 4; ++r) {
                const int i = i0 + it * 16 + g * 4 + r;
                const int c = ct * 16 + r16;
                accBase[(size_t)i * C_ + c] = acc[it][ct][r];
            }
}

// ---------------------------------------------------------------------------
// Combine: out = elu( (sum_p acc_p) / (sum_p l_p) ), float4 per thread
// ---------------------------------------------------------------------------
__global__ __launch_bounds__(256) void gat_combine(
    const float* __restrict__ accP, const float* __restrict__ lP,
    float* __restrict__ out, int jsNum)
{
    const int t = blockIdx.x * 256 + threadIdx.x;      // one float4
    const int total4 = B_ * N_ * C_ / 4;
    if (t >= total4) return;
    const int bi = t >> 4;                             // (t*4)/C_
    float4 asum = {0.f, 0.f, 0.f, 0.f};
    float lsum = 0.f;
    for (int p = 0; p < jsNum; ++p) {
        float4 v = ((const float4*)accP)[(size_t)p * total4 + t];
        asum.x += v.x; asum.y += v.y; asum.z += v.z; asum.w += v.w;
        lsum += lP[(size_t)p * (B_ * N_) + bi];
    }
    const float inv = 1.0f / lsum;
    float4 o;
    o.x = asum.x * inv; o.y = asum.y * inv; o.z = asum.z * inv; o.w = asum.w * inv;
    o.x = (o.x > 0.f) ? o.x : (expf(o.x) - 1.f);
    o.y = (o.y > 0.f) ? o.y : (expf(o.y) - 1.f);
    o.z = (o.z > 0.f) ? o.z : (expf(o.z) - 1.f);
    o.w = (o.w > 0.f) ? o.w : (expf(o.w) - 1.f);
    ((float4*)out)[t] = o;
}

// ---------------------------------------------------------------------------
extern "C" void kernel_launch(void* const* d_in, const int* in_sizes, int n_in,
                              void* d_out, int out_size, void* d_ws, size_t ws_size,
                              hipStream_t stream)
{
    const float* h   = (const float*)d_in[0];   // (B,N,C) f32
    const float* adj = (const float*)d_in[1];   // (N,N)   f32
    const float* a   = (const float*)d_in[2];   // (2C,1)  f32
    float* out = (float*)d_out;

    char* ws = (char*)d_ws;
    float* s1s = (float*)ws;                                    // B*N f32
    float* s2s = (float*)(ws + (size_t)B_ * N_ * 4);            // B*N f32
    unsigned short* hT = (unsigned short*)(ws + (size_t)2 * B_ * N_ * 4);
    const size_t maskOff = (size_t)2 * B_ * N_ * 4 + (size_t)B_ * C_ * N_ * 2;
    unsigned int* maskT = (unsigned int*)(ws + maskOff);        // NW_*N_ u32
    const size_t lOff = maskOff + (size_t)NW_ * N_ * 4;

    int jsNum = 8;
    while (jsNum > 1) {
        size_t need = lOff + (size_t)jsNum * B_ * N_ * 4
                           + (size_t)jsNum * B_ * N_ * C_ * 4;
        if (need <= ws_size) break;
        jsNum >>= 1;
    }
    float* lP   = (float*)(ws + lOff);
    float* accP = (float*)(ws + lOff + (size_t)jsNum * B_ * N_ * 4);

    gat_prep<<<B_ * (N_ / 64), 256, 0, stream>>>(h, a, s1s, s2s, hT);
    gat_mask<<<(N_ / 32) * (N_ / 512), 256, 0, stream>>>(adj, maskT);
    gat_main<<<128 * jsNum, 256, 0, stream>>>(maskT, s1s, s2s, hT, accP, lP, jsNum);
    gat_combine<<<(B_ * N_ * C_ / 4 + 255) / 256, 256, 0, stream>>>(accP, lP, out, jsNum);
}